// Round 11
// baseline (203.226 us; speedup 1.0000x reference)
//
#include <hip/hip_runtime.h>

#define N_NODES 50000
#define N_EDGES 600000
#define D 128
#define K3 (3 * D)
#define CAP 64      // bucket capacity per node (mean deg 12; spill path for overflow)
#define NB_G 1563   // ceil(50000/32): one 32-row gemm tile per block
#define NB_F 586    // ceil((600000/4)/256): fill blocks (4 edges/thread)
#define LDSROW 104  // 96 cols + 8 pad (ushorts); row stride 208B

typedef __attribute__((ext_vector_type(8))) short short8;
typedef __attribute__((ext_vector_type(4))) float floatx4;
typedef __attribute__((ext_vector_type(8))) unsigned short ushort8;

static __device__ __forceinline__ unsigned short f2bf(float f) {
    unsigned u = __float_as_uint(f);
    u += 0x7fff + ((u >> 16) & 1);  // RNE
    return (unsigned short)(u >> 16);
}
static __device__ __forceinline__ float bf2f(unsigned short s) {
    return __uint_as_float(((unsigned)s) << 16);
}
static __device__ __forceinline__ unsigned pack2(float a, float b) {
    return (unsigned)f2bf(a) | ((unsigned)f2bf(b) << 16);
}
static __device__ __forceinline__ short8 cvt8(float4 v0, float4 v1) {
    ushort8 o;
    o[0] = f2bf(v0.x); o[1] = f2bf(v0.y); o[2] = f2bf(v0.z); o[3] = f2bf(v0.w);
    o[4] = f2bf(v1.x); o[5] = f2bf(v1.y); o[6] = f2bf(v1.z); o[7] = f2bf(v1.w);
    return *(short8*)&o;
}

// ---------------- prep: zero cnt+ovfcnt | W->frag-ordered Wr (tiny) -------------
__global__ __launch_bounds__(256) void prep_kernel(const float* __restrict__ W,
                                                   unsigned short* __restrict__ Wr,
                                                   int* __restrict__ cnt) {
    const int stride = gridDim.x * 256;
    const int t0 = blockIdx.x * 256 + threadIdx.x;
    for (int i = t0; i < N_NODES + 4; i += stride) cnt[i] = 0;  // cnt[N] + ovfcnt
    // Wr chunk id = (T*4+ks)*64+lane; value[j] = W[(T&7)*16+c][(T>>3)*128+ks*32+q*8+j]
    for (unsigned id = t0; id < 24u * 4u * 64u; id += stride) {
        unsigned T = id >> 8;
        unsigned ks = (id >> 6) & 3u;
        unsigned lane = id & 63u;
        unsigned c = lane & 15u;
        unsigned q = lane >> 4;
        unsigned row = (T & 7u) * 16u + c;
        unsigned k = (T >> 3) * 128u + ks * 32u + q * 8u;
        const float4 v0 = *(const float4*)(W + (size_t)row * K3 + k);
        const float4 v1 = *(const float4*)(W + (size_t)row * K3 + k + 4);
        short8 o = cvt8(v0, v1);
        *(short8*)(Wr + (size_t)id * 8) = o;
    }
}

// ------- fused: GEMM (blocks<NB_G) || bucket-CSR fill (rest) --------------------
// GEMM: z[N,384] = bf16(x) @ Wcat^T (+bias cols<128); 32 rows/block, reg-hoisted.
// Fill: atomic IS the cursor; fill blocks idle all pipes (atomic-latency-bound),
// so co-residency with gemm blocks hides them under MFMA/BW work.
__global__ __launch_bounds__(256) void gemmfill_kernel(const float* __restrict__ x,
                                                       const unsigned short* __restrict__ Wr,
                                                       const float* __restrict__ bias,
                                                       const int* __restrict__ src,
                                                       const int* __restrict__ dst,
                                                       int* __restrict__ cnt,
                                                       int* __restrict__ bucket,
                                                       int2* __restrict__ ovf,
                                                       unsigned short* __restrict__ z) {
    __shared__ unsigned short lds[4 * 32 * LDSROW];
    const int blk = blockIdx.x;
    const int tid = threadIdx.x;
    if (blk >= NB_G) {
        // ---- bucket-CSR fill: 4 edges/thread, atomics issued before stores ----
        int* ovfcnt = cnt + N_NODES;
        int u = (blk - NB_G) * 256 + tid;
        if (u < N_EDGES / 4) {
            int4 s4 = ((const int4*)src)[u];
            int4 d4 = ((const int4*)dst)[u];
            int p0 = atomicAdd(&cnt[d4.x], 1);
            int p1 = atomicAdd(&cnt[d4.y], 1);
            int p2 = atomicAdd(&cnt[d4.z], 1);
            int p3 = atomicAdd(&cnt[d4.w], 1);
            if (p0 < CAP) bucket[(size_t)d4.x * CAP + p0] = s4.x;
            else ovf[atomicAdd(ovfcnt, 1)] = make_int2(d4.x, s4.x);
            if (p1 < CAP) bucket[(size_t)d4.y * CAP + p1] = s4.y;
            else ovf[atomicAdd(ovfcnt, 1)] = make_int2(d4.y, s4.y);
            if (p2 < CAP) bucket[(size_t)d4.z * CAP + p2] = s4.z;
            else ovf[atomicAdd(ovfcnt, 1)] = make_int2(d4.z, s4.z);
            if (p3 < CAP) bucket[(size_t)d4.w * CAP + p3] = s4.w;
            else ovf[atomicAdd(ovfcnt, 1)] = make_int2(d4.w, s4.w);
        }
        return;
    }
    const int wave = tid >> 6;
    const int lane = tid & 63;
    const int col = lane & 15;
    const int quad = lane >> 4;
    const int mbase = blk * 32;
    const int T0 = wave * 6;  // colblocks [T0, T0+6) => global cols [wave*96, +96)

    int r0 = mbase + col;
    int r1 = mbase + 16 + col;
    if (r0 >= N_NODES) r0 = N_NODES - 1;  // clamp loads; stores guarded
    if (r1 >= N_NODES) r1 = N_NODES - 1;
    const float* ap0 = x + (size_t)r0 * D + quad * 8;
    const float* ap1 = x + (size_t)r1 * D + quad * 8;

    // A fragments: fp32 load + in-register bf16 convert (no staging)
    short8 a0r[4], a1r[4];
#pragma unroll
    for (int ks = 0; ks < 4; ++ks) {
        a0r[ks] = cvt8(*(const float4*)(ap0 + ks * 32), *(const float4*)(ap0 + ks * 32 + 4));
        a1r[ks] = cvt8(*(const float4*)(ap1 + ks * 32), *(const float4*)(ap1 + ks * 32 + 4));
    }
    // B fragments for this wave's 96 columns (L2-resident Wr)
    short8 br[24];
#pragma unroll
    for (int t = 0; t < 6; ++t)
#pragma unroll
        for (int ks = 0; ks < 4; ++ks)
            br[t * 4 + ks] = *(const short8*)(Wr + (size_t)(((T0 + t) * 4 + ks) * 64 + lane) * 8);

    floatx4 acc0[6], acc1[6];
#pragma unroll
    for (int t = 0; t < 6; ++t) {
        acc0[t] = (floatx4){0.f, 0.f, 0.f, 0.f};
        acc1[t] = (floatx4){0.f, 0.f, 0.f, 0.f};
    }
#pragma unroll
    for (int ks = 0; ks < 4; ++ks) {
#pragma unroll
        for (int t = 0; t < 6; ++t) {
            // swapped operands: lane owns 4 consecutive output cols
            acc0[t] = __builtin_amdgcn_mfma_f32_16x16x32_bf16(br[t * 4 + ks], a0r[ks], acc0[t], 0, 0, 0);
            acc1[t] = __builtin_amdgcn_mfma_f32_16x16x32_bf16(br[t * 4 + ks], a1r[ks], acc1[t], 0, 0, 0);
        }
    }

    // epilogue: lane's acc[t][r] = z[node][j], node=mbase+col (+16), j=(T0+t)*16+quad*4+r
    unsigned short* wlds = lds + wave * 32 * LDSROW;
#pragma unroll
    for (int t = 0; t < 6; ++t) {
        int T = T0 + t;
        float4 bq = (float4){0.f, 0.f, 0.f, 0.f};
        if (T < 8) bq = *(const float4*)(bias + T * 16 + quad * 4);
        uint2 p;
        p.x = pack2(acc0[t][0] + bq.x, acc0[t][1] + bq.y);
        p.y = pack2(acc0[t][2] + bq.z, acc0[t][3] + bq.w);
        *(uint2*)(wlds + col * LDSROW + t * 16 + quad * 4) = p;
        uint2 q2;
        q2.x = pack2(acc1[t][0] + bq.x, acc1[t][1] + bq.y);
        q2.y = pack2(acc1[t][2] + bq.z, acc1[t][3] + bq.w);
        *(uint2*)(wlds + (col + 16) * LDSROW + t * 16 + quad * 4) = q2;
    }
    __syncthreads();
    // block-wide readback: 32 rows x 48 chunks(16B) = full 768B rows, coalesced
#pragma unroll
    for (int it = 0; it < 6; ++it) {
        int id = it * 256 + tid;
        int row = id / 48;
        int ch = id - row * 48;
        int w = ch / 12;
        int cc = (ch - w * 12) * 8;  // ushort offset within wave's 96 cols
        int node = mbase + row;
        ushort8 v = *(const ushort8*)(lds + (size_t)w * 32 * LDSROW + row * LDSROW + cc);
        if (node < N_NODES)
            *(ushort8*)(z + (size_t)node * K3 + ch * 8) = v;
    }
}

// ---------------- gather1: tb = z2 + P z3  (bf16 out) ----------------
// one wave/node; lane = slot*16 + colchunk; bucket rows are 16B-aligned.
__global__ __launch_bounds__(256) void gather1_kernel(const unsigned short* __restrict__ z,
                                                      const int* __restrict__ cnt,
                                                      const int* __restrict__ bucket,
                                                      const int2* __restrict__ ovf,
                                                      unsigned short* __restrict__ tb) {
    unsigned n = (blockIdx.x * 256 + threadIdx.x) >> 6;
    if (n >= N_NODES) return;
    const int lane = threadIdx.x & 63;
    const int s = lane >> 4;
    const unsigned c = (lane & 15u) << 3;
    const unsigned short* fin = z + 256 + c;  // z3 cols
    const int deg = cnt[n];
    const int dcap = min(deg, CAP);
    const int* bp = bucket + (size_t)n * CAP;
    float acc[8] = {0.f, 0.f, 0.f, 0.f, 0.f, 0.f, 0.f, 0.f};
    for (int base = s * 4; base < dcap; base += 16) {
        int4 idx = *(const int4*)(bp + base);
        float m0 = 1.f;  // base < dcap guaranteed
        float m1 = (base + 1 < dcap) ? 1.f : 0.f;
        float m2 = (base + 2 < dcap) ? 1.f : 0.f;
        float m3 = (base + 3 < dcap) ? 1.f : 0.f;
        int s0 = min(max(idx.x, 0), N_NODES - 1);
        int s1 = min(max(idx.y, 0), N_NODES - 1);
        int s2 = min(max(idx.z, 0), N_NODES - 1);
        int s3 = min(max(idx.w, 0), N_NODES - 1);
        ushort8 v0 = *(const ushort8*)(fin + (size_t)s0 * K3);
        ushort8 v1 = *(const ushort8*)(fin + (size_t)s1 * K3);
        ushort8 v2 = *(const ushort8*)(fin + (size_t)s2 * K3);
        ushort8 v3 = *(const ushort8*)(fin + (size_t)s3 * K3);
#pragma unroll
        for (int j = 0; j < 8; ++j)
            acc[j] += (m0 * bf2f(v0[j]) + m1 * bf2f(v1[j])) +
                      (m2 * bf2f(v2[j]) + m3 * bf2f(v3[j]));
    }
    if (deg > CAP) {  // spill path (never taken for this input; correct in general)
        int oc = cnt[N_NODES];
        if (s == 0)
            for (int i = 0; i < oc; ++i) {
                int2 p = ovf[i];
                if (p.x == (int)n) {
                    ushort8 v = *(const ushort8*)(fin + (size_t)p.y * K3);
#pragma unroll
                    for (int j = 0; j < 8; ++j) acc[j] += bf2f(v[j]);
                }
            }
    }
#pragma unroll
    for (int j = 0; j < 8; ++j) {
        acc[j] += __shfl_xor(acc[j], 16);
        acc[j] += __shfl_xor(acc[j], 32);
    }
    if (s == 0) {
        float inv = 1.0f / fmaxf((float)deg, 1.0f);
        ushort8 za = *(const ushort8*)(z + (size_t)n * K3 + 128 + c);  // z2
        ushort8 o;
#pragma unroll
        for (int j = 0; j < 8; ++j) o[j] = f2bf(bf2f(za[j]) + acc[j] * inv);
        *(ushort8*)(tb + (size_t)n * D + c) = o;
    }
}

// ---------------- gather2: out = z1 + P tb  (fp32 out, final) ----------------
__global__ __launch_bounds__(256) void gather2_kernel(const unsigned short* __restrict__ z,
                                                      const unsigned short* __restrict__ tb,
                                                      const int* __restrict__ cnt,
                                                      const int* __restrict__ bucket,
                                                      const int2* __restrict__ ovf,
                                                      float* __restrict__ out) {
    unsigned n = (blockIdx.x * 256 + threadIdx.x) >> 6;
    if (n >= N_NODES) return;
    const int lane = threadIdx.x & 63;
    const int s = lane >> 4;
    const unsigned c = (lane & 15u) << 3;
    const unsigned short* fin = tb + c;
    const int deg = cnt[n];
    const int dcap = min(deg, CAP);
    const int* bp = bucket + (size_t)n * CAP;
    float acc[8] = {0.f, 0.f, 0.f, 0.f, 0.f, 0.f, 0.f, 0.f};
    for (int base = s * 4; base < dcap; base += 16) {
        int4 idx = *(const int4*)(bp + base);
        float m0 = 1.f;
        float m1 = (base + 1 < dcap) ? 1.f : 0.f;
        float m2 = (base + 2 < dcap) ? 1.f : 0.f;
        float m3 = (base + 3 < dcap) ? 1.f : 0.f;
        int s0 = min(max(idx.x, 0), N_NODES - 1);
        int s1 = min(max(idx.y, 0), N_NODES - 1);
        int s2 = min(max(idx.z, 0), N_NODES - 1);
        int s3 = min(max(idx.w, 0), N_NODES - 1);
        ushort8 v0 = *(const ushort8*)(fin + (size_t)s0 * D);
        ushort8 v1 = *(const ushort8*)(fin + (size_t)s1 * D);
        ushort8 v2 = *(const ushort8*)(fin + (size_t)s2 * D);
        ushort8 v3 = *(const ushort8*)(fin + (size_t)s3 * D);
#pragma unroll
        for (int j = 0; j < 8; ++j)
            acc[j] += (m0 * bf2f(v0[j]) + m1 * bf2f(v1[j])) +
                      (m2 * bf2f(v2[j]) + m3 * bf2f(v3[j]));
    }
    if (deg > CAP) {
        int oc = cnt[N_NODES];
        if (s == 0)
            for (int i = 0; i < oc; ++i) {
                int2 p = ovf[i];
                if (p.x == (int)n) {
                    ushort8 v = *(const ushort8*)(fin + (size_t)p.y * D);
#pragma unroll
                    for (int j = 0; j < 8; ++j) acc[j] += bf2f(v[j]);
                }
            }
    }
#pragma unroll
    for (int j = 0; j < 8; ++j) {
        acc[j] += __shfl_xor(acc[j], 16);
        acc[j] += __shfl_xor(acc[j], 32);
    }
    if (s == 0) {
        float inv = 1.0f / fmaxf((float)deg, 1.0f);
        ushort8 za = *(const ushort8*)(z + (size_t)n * K3 + c);  // z1 (+bias)
        float4 q0, q1;
        q0.x = bf2f(za[0]) + acc[0] * inv;
        q0.y = bf2f(za[1]) + acc[1] * inv;
        q0.z = bf2f(za[2]) + acc[2] * inv;
        q0.w = bf2f(za[3]) + acc[3] * inv;
        q1.x = bf2f(za[4]) + acc[4] * inv;
        q1.y = bf2f(za[5]) + acc[5] * inv;
        q1.z = bf2f(za[6]) + acc[6] * inv;
        q1.w = bf2f(za[7]) + acc[7] * inv;
        *(float4*)(out + (size_t)n * D + c) = q0;
        *(float4*)(out + (size_t)n * D + c + 4) = q1;
    }
}

extern "C" void kernel_launch(void* const* d_in, const int* in_sizes, int n_in,
                              void* d_out, int out_size, void* d_ws, size_t ws_size,
                              hipStream_t stream) {
    const float* x = (const float*)d_in[0];
    const int* ei = (const int*)d_in[1];
    const float* W = (const float*)d_in[2];
    const float* b = (const float*)d_in[3];
    float* out = (float*)d_out;
    const int* src = ei;            // edge_index[0,:]
    const int* dst = ei + N_EDGES;  // edge_index[1,:]

    // workspace layout:
    //   z [N,384] bf16 | tb [N,128] bf16 | Wr 6144x16B
    //   cnt [N] + ovfcnt [4] | bucket [N*64] | ovf [E int2]
    unsigned short* z = (unsigned short*)d_ws;
    unsigned short* tb = z + (size_t)N_NODES * K3;
    unsigned short* Wr = tb + (size_t)N_NODES * D;
    int* cnt = (int*)(Wr + 6144 * 8);
    int* bucket = cnt + N_NODES + 4;          // 16B-aligned (N+4 ints from aligned base)
    int2* ovf = (int2*)(bucket + (size_t)N_NODES * CAP);

    prep_kernel<<<200, 256, 0, stream>>>(W, Wr, cnt);
    gemmfill_kernel<<<NB_G + NB_F, 256, 0, stream>>>(x, Wr, b, src, dst, cnt, bucket, ovf, z);

    const int ggrid = (N_NODES * 64 + 255) / 256;  // one wave per node
    gather1_kernel<<<ggrid, 256, 0, stream>>>(z, cnt, bucket, ovf, tb);
    gather2_kernel<<<ggrid, 256, 0, stream>>>(z, tb, cnt, bucket, ovf, out);
}

// Round 12
// 190.384 us; speedup vs baseline: 1.0675x; 1.0675x over previous
//
#include <hip/hip_runtime.h>

#define N_NODES 50000
#define N_EDGES 600000
#define D 128
#define K3 (3 * D)
#define CAP 64      // bucket capacity per node (mean deg 12; spill path for overflow)
#define NB_G 1563   // ceil(50000/32): one 32-row gemm tile per block (max TLP)
#define LDSROW 104  // 96 cols + 8 pad (ushorts); row stride 208B

typedef __attribute__((ext_vector_type(8))) short short8;
typedef __attribute__((ext_vector_type(4))) float floatx4;
typedef __attribute__((ext_vector_type(8))) unsigned short ushort8;

static __device__ __forceinline__ unsigned short f2bf(float f) {
    unsigned u = __float_as_uint(f);
    u += 0x7fff + ((u >> 16) & 1);  // RNE
    return (unsigned short)(u >> 16);
}
static __device__ __forceinline__ float bf2f(unsigned short s) {
    return __uint_as_float(((unsigned)s) << 16);
}
static __device__ __forceinline__ unsigned pack2(float a, float b) {
    return (unsigned)f2bf(a) | ((unsigned)f2bf(b) << 16);
}
static __device__ __forceinline__ short8 cvt8(float4 v0, float4 v1) {
    ushort8 o;
    o[0] = f2bf(v0.x); o[1] = f2bf(v0.y); o[2] = f2bf(v0.z); o[3] = f2bf(v0.w);
    o[4] = f2bf(v1.x); o[5] = f2bf(v1.y); o[6] = f2bf(v1.z); o[7] = f2bf(v1.w);
    return *(short8*)&o;
}

// ---------------- prep: zero cnt+ovfcnt | W->frag-ordered Wr (tiny) -------------
__global__ __launch_bounds__(256) void prep_kernel(const float* __restrict__ W,
                                                   unsigned short* __restrict__ Wr,
                                                   int* __restrict__ cnt) {
    const int stride = gridDim.x * 256;
    const int t0 = blockIdx.x * 256 + threadIdx.x;
    for (int i = t0; i < N_NODES + 4; i += stride) cnt[i] = 0;  // cnt[N] + ovfcnt
    // Wr chunk id = (T*4+ks)*64+lane; value[j] = W[(T&7)*16+c][(T>>3)*128+ks*32+q*8+j]
    for (unsigned id = t0; id < 24u * 4u * 64u; id += stride) {
        unsigned T = id >> 8;
        unsigned ks = (id >> 6) & 3u;
        unsigned lane = id & 63u;
        unsigned c = lane & 15u;
        unsigned q = lane >> 4;
        unsigned row = (T & 7u) * 16u + c;
        unsigned k = (T >> 3) * 128u + ks * 32u + q * 8u;
        const float4 v0 = *(const float4*)(W + (size_t)row * K3 + k);
        const float4 v1 = *(const float4*)(W + (size_t)row * K3 + k + 4);
        short8 o = cvt8(v0, v1);
        *(short8*)(Wr + (size_t)id * 8) = o;
    }
}

// -------- bucket-CSR fill: 1 edge/thread (latency-bound -> maximize TLP) --------
// R10's 4-edge/thread version ran at 20% occupancy (586 blocks = 9 waves/CU);
// 2344 blocks give ~32 resident waves/CU to hide the atomic round-trips.
__global__ __launch_bounds__(256) void fillb_kernel(const int* __restrict__ src,
                                                    const int* __restrict__ dst,
                                                    int* __restrict__ cnt,
                                                    int* __restrict__ bucket,
                                                    int2* __restrict__ ovf) {
    int* ovfcnt = cnt + N_NODES;
    int e = blockIdx.x * 256 + threadIdx.x;
    if (e < N_EDGES) {
        int d = dst[e];
        int s = src[e];
        int p = atomicAdd(&cnt[d], 1);
        if (p < CAP) bucket[(size_t)d * CAP + p] = s;
        else ovf[atomicAdd(ovfcnt, 1)] = make_int2(d, s);
    }
}

// ------- GEMM: z[N,384] = bf16(x) @ Wcat^T (+bias cols<128) ---------------------
// 1563 blocks x one 32-row tile; br[24] register-hoisted (VGPR 136 — check this
// stays >130 after any future edit; regalloc dropping it costs 2x, see R11).
__global__ __launch_bounds__(256) void gemm_kernel(const float* __restrict__ x,
                                                   const unsigned short* __restrict__ Wr,
                                                   const float* __restrict__ bias,
                                                   unsigned short* __restrict__ z) {
    __shared__ unsigned short lds[4 * 32 * LDSROW];
    const int tid = threadIdx.x;
    const int wave = tid >> 6;
    const int lane = tid & 63;
    const int col = lane & 15;
    const int quad = lane >> 4;
    const int mbase = blockIdx.x * 32;
    const int T0 = wave * 6;  // colblocks [T0, T0+6) => global cols [wave*96, +96)

    int r0 = mbase + col;
    int r1 = mbase + 16 + col;
    if (r0 >= N_NODES) r0 = N_NODES - 1;  // clamp loads; stores guarded
    if (r1 >= N_NODES) r1 = N_NODES - 1;
    const float* ap0 = x + (size_t)r0 * D + quad * 8;
    const float* ap1 = x + (size_t)r1 * D + quad * 8;

    // A fragments: fp32 load + in-register bf16 convert (no staging)
    short8 a0r[4], a1r[4];
#pragma unroll
    for (int ks = 0; ks < 4; ++ks) {
        a0r[ks] = cvt8(*(const float4*)(ap0 + ks * 32), *(const float4*)(ap0 + ks * 32 + 4));
        a1r[ks] = cvt8(*(const float4*)(ap1 + ks * 32), *(const float4*)(ap1 + ks * 32 + 4));
    }
    // B fragments for this wave's 96 columns (L2-resident Wr)
    short8 br[24];
#pragma unroll
    for (int t = 0; t < 6; ++t)
#pragma unroll
        for (int ks = 0; ks < 4; ++ks)
            br[t * 4 + ks] = *(const short8*)(Wr + (size_t)(((T0 + t) * 4 + ks) * 64 + lane) * 8);

    floatx4 acc0[6], acc1[6];
#pragma unroll
    for (int t = 0; t < 6; ++t) {
        acc0[t] = (floatx4){0.f, 0.f, 0.f, 0.f};
        acc1[t] = (floatx4){0.f, 0.f, 0.f, 0.f};
    }
#pragma unroll
    for (int ks = 0; ks < 4; ++ks) {
#pragma unroll
        for (int t = 0; t < 6; ++t) {
            // swapped operands: lane owns 4 consecutive output cols
            acc0[t] = __builtin_amdgcn_mfma_f32_16x16x32_bf16(br[t * 4 + ks], a0r[ks], acc0[t], 0, 0, 0);
            acc1[t] = __builtin_amdgcn_mfma_f32_16x16x32_bf16(br[t * 4 + ks], a1r[ks], acc1[t], 0, 0, 0);
        }
    }

    // epilogue: lane's acc[t][r] = z[node][j], node=mbase+col (+16), j=(T0+t)*16+quad*4+r
    unsigned short* wlds = lds + wave * 32 * LDSROW;
#pragma unroll
    for (int t = 0; t < 6; ++t) {
        int T = T0 + t;
        float4 bq = (float4){0.f, 0.f, 0.f, 0.f};
        if (T < 8) bq = *(const float4*)(bias + T * 16 + quad * 4);
        uint2 p;
        p.x = pack2(acc0[t][0] + bq.x, acc0[t][1] + bq.y);
        p.y = pack2(acc0[t][2] + bq.z, acc0[t][3] + bq.w);
        *(uint2*)(wlds + col * LDSROW + t * 16 + quad * 4) = p;
        uint2 q2;
        q2.x = pack2(acc1[t][0] + bq.x, acc1[t][1] + bq.y);
        q2.y = pack2(acc1[t][2] + bq.z, acc1[t][3] + bq.w);
        *(uint2*)(wlds + (col + 16) * LDSROW + t * 16 + quad * 4) = q2;
    }
    __syncthreads();
    // block-wide readback: 32 rows x 48 chunks(16B) = full 768B rows, coalesced
#pragma unroll
    for (int it = 0; it < 6; ++it) {
        int id = it * 256 + tid;
        int row = id / 48;
        int ch = id - row * 48;
        int w = ch / 12;
        int cc = (ch - w * 12) * 8;  // ushort offset within wave's 96 cols
        int node = mbase + row;
        ushort8 v = *(const ushort8*)(lds + (size_t)w * 32 * LDSROW + row * LDSROW + cc);
        if (node < N_NODES)
            *(ushort8*)(z + (size_t)node * K3 + ch * 8) = v;
    }
}

// ---------------- gather1: tb = z2 + P z3  (bf16 out) ----------------
// one wave/node; lane = slot*16 + colchunk; bucket rows are 16B-aligned.
__global__ __launch_bounds__(256) void gather1_kernel(const unsigned short* __restrict__ z,
                                                      const int* __restrict__ cnt,
                                                      const int* __restrict__ bucket,
                                                      const int2* __restrict__ ovf,
                                                      unsigned short* __restrict__ tb) {
    unsigned n = (blockIdx.x * 256 + threadIdx.x) >> 6;
    if (n >= N_NODES) return;
    const int lane = threadIdx.x & 63;
    const int s = lane >> 4;
    const unsigned c = (lane & 15u) << 3;
    const unsigned short* fin = z + 256 + c;  // z3 cols
    const int deg = cnt[n];
    const int dcap = min(deg, CAP);
    const int* bp = bucket + (size_t)n * CAP;
    float acc[8] = {0.f, 0.f, 0.f, 0.f, 0.f, 0.f, 0.f, 0.f};
    for (int base = s * 4; base < dcap; base += 16) {
        int4 idx = *(const int4*)(bp + base);
        float m0 = 1.f;  // base < dcap guaranteed
        float m1 = (base + 1 < dcap) ? 1.f : 0.f;
        float m2 = (base + 2 < dcap) ? 1.f : 0.f;
        float m3 = (base + 3 < dcap) ? 1.f : 0.f;
        int s0 = min(max(idx.x, 0), N_NODES - 1);
        int s1 = min(max(idx.y, 0), N_NODES - 1);
        int s2 = min(max(idx.z, 0), N_NODES - 1);
        int s3 = min(max(idx.w, 0), N_NODES - 1);
        ushort8 v0 = *(const ushort8*)(fin + (size_t)s0 * K3);
        ushort8 v1 = *(const ushort8*)(fin + (size_t)s1 * K3);
        ushort8 v2 = *(const ushort8*)(fin + (size_t)s2 * K3);
        ushort8 v3 = *(const ushort8*)(fin + (size_t)s3 * K3);
#pragma unroll
        for (int j = 0; j < 8; ++j)
            acc[j] += (m0 * bf2f(v0[j]) + m1 * bf2f(v1[j])) +
                      (m2 * bf2f(v2[j]) + m3 * bf2f(v3[j]));
    }
    if (deg > CAP) {  // spill path (never taken for this input; correct in general)
        int oc = cnt[N_NODES];
        if (s == 0)
            for (int i = 0; i < oc; ++i) {
                int2 p = ovf[i];
                if (p.x == (int)n) {
                    ushort8 v = *(const ushort8*)(fin + (size_t)p.y * K3);
#pragma unroll
                    for (int j = 0; j < 8; ++j) acc[j] += bf2f(v[j]);
                }
            }
    }
#pragma unroll
    for (int j = 0; j < 8; ++j) {
        acc[j] += __shfl_xor(acc[j], 16);
        acc[j] += __shfl_xor(acc[j], 32);
    }
    if (s == 0) {
        float inv = 1.0f / fmaxf((float)deg, 1.0f);
        ushort8 za = *(const ushort8*)(z + (size_t)n * K3 + 128 + c);  // z2
        ushort8 o;
#pragma unroll
        for (int j = 0; j < 8; ++j) o[j] = f2bf(bf2f(za[j]) + acc[j] * inv);
        *(ushort8*)(tb + (size_t)n * D + c) = o;
    }
}

// ---------------- gather2: out = z1 + P tb  (fp32 out, final) ----------------
__global__ __launch_bounds__(256) void gather2_kernel(const unsigned short* __restrict__ z,
                                                      const unsigned short* __restrict__ tb,
                                                      const int* __restrict__ cnt,
                                                      const int* __restrict__ bucket,
                                                      const int2* __restrict__ ovf,
                                                      float* __restrict__ out) {
    unsigned n = (blockIdx.x * 256 + threadIdx.x) >> 6;
    if (n >= N_NODES) return;
    const int lane = threadIdx.x & 63;
    const int s = lane >> 4;
    const unsigned c = (lane & 15u) << 3;
    const unsigned short* fin = tb + c;
    const int deg = cnt[n];
    const int dcap = min(deg, CAP);
    const int* bp = bucket + (size_t)n * CAP;
    float acc[8] = {0.f, 0.f, 0.f, 0.f, 0.f, 0.f, 0.f, 0.f};
    for (int base = s * 4; base < dcap; base += 16) {
        int4 idx = *(const int4*)(bp + base);
        float m0 = 1.f;
        float m1 = (base + 1 < dcap) ? 1.f : 0.f;
        float m2 = (base + 2 < dcap) ? 1.f : 0.f;
        float m3 = (base + 3 < dcap) ? 1.f : 0.f;
        int s0 = min(max(idx.x, 0), N_NODES - 1);
        int s1 = min(max(idx.y, 0), N_NODES - 1);
        int s2 = min(max(idx.z, 0), N_NODES - 1);
        int s3 = min(max(idx.w, 0), N_NODES - 1);
        ushort8 v0 = *(const ushort8*)(fin + (size_t)s0 * D);
        ushort8 v1 = *(const ushort8*)(fin + (size_t)s1 * D);
        ushort8 v2 = *(const ushort8*)(fin + (size_t)s2 * D);
        ushort8 v3 = *(const ushort8*)(fin + (size_t)s3 * D);
#pragma unroll
        for (int j = 0; j < 8; ++j)
            acc[j] += (m0 * bf2f(v0[j]) + m1 * bf2f(v1[j])) +
                      (m2 * bf2f(v2[j]) + m3 * bf2f(v3[j]));
    }
    if (deg > CAP) {
        int oc = cnt[N_NODES];
        if (s == 0)
            for (int i = 0; i < oc; ++i) {
                int2 p = ovf[i];
                if (p.x == (int)n) {
                    ushort8 v = *(const ushort8*)(fin + (size_t)p.y * D);
#pragma unroll
                    for (int j = 0; j < 8; ++j) acc[j] += bf2f(v[j]);
                }
            }
    }
#pragma unroll
    for (int j = 0; j < 8; ++j) {
        acc[j] += __shfl_xor(acc[j], 16);
        acc[j] += __shfl_xor(acc[j], 32);
    }
    if (s == 0) {
        float inv = 1.0f / fmaxf((float)deg, 1.0f);
        ushort8 za = *(const ushort8*)(z + (size_t)n * K3 + c);  // z1 (+bias)
        float4 q0, q1;
        q0.x = bf2f(za[0]) + acc[0] * inv;
        q0.y = bf2f(za[1]) + acc[1] * inv;
        q0.z = bf2f(za[2]) + acc[2] * inv;
        q0.w = bf2f(za[3]) + acc[3] * inv;
        q1.x = bf2f(za[4]) + acc[4] * inv;
        q1.y = bf2f(za[5]) + acc[5] * inv;
        q1.z = bf2f(za[6]) + acc[6] * inv;
        q1.w = bf2f(za[7]) + acc[7] * inv;
        *(float4*)(out + (size_t)n * D + c) = q0;
        *(float4*)(out + (size_t)n * D + c + 4) = q1;
    }
}

extern "C" void kernel_launch(void* const* d_in, const int* in_sizes, int n_in,
                              void* d_out, int out_size, void* d_ws, size_t ws_size,
                              hipStream_t stream) {
    const float* x = (const float*)d_in[0];
    const int* ei = (const int*)d_in[1];
    const float* W = (const float*)d_in[2];
    const float* b = (const float*)d_in[3];
    float* out = (float*)d_out;
    const int* src = ei;            // edge_index[0,:]
    const int* dst = ei + N_EDGES;  // edge_index[1,:]

    // workspace layout:
    //   z [N,384] bf16 | tb [N,128] bf16 | Wr 6144x16B
    //   cnt [N] + ovfcnt [4] | bucket [N*64] | ovf [E int2]
    unsigned short* z = (unsigned short*)d_ws;
    unsigned short* tb = z + (size_t)N_NODES * K3;
    unsigned short* Wr = tb + (size_t)N_NODES * D;
    int* cnt = (int*)(Wr + 6144 * 8);
    int* bucket = cnt + N_NODES + 4;          // 16B-aligned (N+4 ints from aligned base)
    int2* ovf = (int2*)(bucket + (size_t)N_NODES * CAP);

    prep_kernel<<<200, 256, 0, stream>>>(W, Wr, cnt);
    fillb_kernel<<<(N_EDGES + 255) / 256, 256, 0, stream>>>(src, dst, cnt, bucket, ovf);
    gemm_kernel<<<NB_G, 256, 0, stream>>>(x, Wr, b, z);

    const int ggrid = (N_NODES * 64 + 255) / 256;  // one wave per node
    gather1_kernel<<<ggrid, 256, 0, stream>>>(z, cnt, bucket, ovf, tb);
    gather2_kernel<<<ggrid, 256, 0, stream>>>(z, tb, cnt, bucket, ovf, out);
}

// Round 13
// 175.000 us; speedup vs baseline: 1.1613x; 1.0879x over previous
//
#include <hip/hip_runtime.h>

#define N_NODES 50000
#define N_EDGES 600000
#define D 128
#define K3 (3 * D)
#define CAP 64      // bucket capacity per node (mean deg 12; spill path for overflow)
#define NB_G 1563   // ceil(50000/32): one 32-row gemm tile per block (max TLP)
#define EPB 384     // edges per gemm block: 1563*384 = 600,192 >= N_EDGES
#define LDSROW 104  // 96 cols + 8 pad (ushorts); row stride 208B

typedef __attribute__((ext_vector_type(8))) short short8;
typedef __attribute__((ext_vector_type(4))) float floatx4;
typedef __attribute__((ext_vector_type(8))) unsigned short ushort8;

static __device__ __forceinline__ unsigned short f2bf(float f) {
    unsigned u = __float_as_uint(f);
    u += 0x7fff + ((u >> 16) & 1);  // RNE
    return (unsigned short)(u >> 16);
}
static __device__ __forceinline__ float bf2f(unsigned short s) {
    return __uint_as_float(((unsigned)s) << 16);
}
static __device__ __forceinline__ unsigned pack2(float a, float b) {
    return (unsigned)f2bf(a) | ((unsigned)f2bf(b) << 16);
}
static __device__ __forceinline__ short8 cvt8(float4 v0, float4 v1) {
    ushort8 o;
    o[0] = f2bf(v0.x); o[1] = f2bf(v0.y); o[2] = f2bf(v0.z); o[3] = f2bf(v0.w);
    o[4] = f2bf(v1.x); o[5] = f2bf(v1.y); o[6] = f2bf(v1.z); o[7] = f2bf(v1.w);
    return *(short8*)&o;
}

// ---------------- prep: zero cnt+ovfcnt | W->frag-ordered Wr (tiny) -------------
__global__ __launch_bounds__(256) void prep_kernel(const float* __restrict__ W,
                                                   unsigned short* __restrict__ Wr,
                                                   int* __restrict__ cnt) {
    const int stride = gridDim.x * 256;
    const int t0 = blockIdx.x * 256 + threadIdx.x;
    for (int i = t0; i < N_NODES + 4; i += stride) cnt[i] = 0;  // cnt[N] + ovfcnt
    // Wr chunk id = (T*4+ks)*64+lane; value[j] = W[(T&7)*16+c][(T>>3)*128+ks*32+q*8+j]
    for (unsigned id = t0; id < 24u * 4u * 64u; id += stride) {
        unsigned T = id >> 8;
        unsigned ks = (id >> 6) & 3u;
        unsigned lane = id & 63u;
        unsigned c = lane & 15u;
        unsigned q = lane >> 4;
        unsigned row = (T & 7u) * 16u + c;
        unsigned k = (T >> 3) * 128u + ks * 32u + q * 8u;
        const float4 v0 = *(const float4*)(W + (size_t)row * K3 + k);
        const float4 v1 = *(const float4*)(W + (size_t)row * K3 + k + 4);
        short8 o = cvt8(v0, v1);
        *(short8*)(Wr + (size_t)id * 8) = o;
    }
}

// ------- GEMM + inlined bucket-CSR fill (single code path, R11 lesson) ----------
// GEMM: z[N,384] = bf16(x) @ Wcat^T (+bias cols<128); 32 rows/block, reg-hoisted
// br[24] (VGPR canary: must stay >~130; R11's branch-fusion dropped it to 76).
// Fill: each block also buckets a 384-edge chunk; atomic latency hides under
// the block's own fragment loads + MFMA.
__global__ __launch_bounds__(256) void gemmfill_kernel(const float* __restrict__ x,
                                                       const unsigned short* __restrict__ Wr,
                                                       const float* __restrict__ bias,
                                                       const int* __restrict__ src,
                                                       const int* __restrict__ dst,
                                                       int* __restrict__ cnt,
                                                       int* __restrict__ bucket,
                                                       int2* __restrict__ ovf,
                                                       unsigned short* __restrict__ z) {
    __shared__ unsigned short lds[4 * 32 * LDSROW];
    const int tid = threadIdx.x;
    const int wave = tid >> 6;
    const int lane = tid & 63;
    const int col = lane & 15;
    const int quad = lane >> 4;
    const int mbase = blockIdx.x * 32;
    const int T0 = wave * 6;  // colblocks [T0, T0+6) => global cols [wave*96, +96)

    int r0 = mbase + col;
    int r1 = mbase + 16 + col;
    if (r0 >= N_NODES) r0 = N_NODES - 1;  // clamp loads; stores guarded
    if (r1 >= N_NODES) r1 = N_NODES - 1;
    const float* ap0 = x + (size_t)r0 * D + quad * 8;
    const float* ap1 = x + (size_t)r1 * D + quad * 8;

    // A fragments: fp32 load + in-register bf16 convert (no staging)
    short8 a0r[4], a1r[4];
#pragma unroll
    for (int ks = 0; ks < 4; ++ks) {
        a0r[ks] = cvt8(*(const float4*)(ap0 + ks * 32), *(const float4*)(ap0 + ks * 32 + 4));
        a1r[ks] = cvt8(*(const float4*)(ap1 + ks * 32), *(const float4*)(ap1 + ks * 32 + 4));
    }
    // B fragments for this wave's 96 columns (L2-resident Wr)
    short8 br[24];
#pragma unroll
    for (int t = 0; t < 6; ++t)
#pragma unroll
        for (int ks = 0; ks < 4; ++ks)
            br[t * 4 + ks] = *(const short8*)(Wr + (size_t)(((T0 + t) * 4 + ks) * 64 + lane) * 8);

    // ---- inlined fill: this block's 384-edge chunk (1.5 edges/thread) ----
    {
        int* ovfcnt = cnt + N_NODES;
        const int ebase = blockIdx.x * EPB;
        int e0 = ebase + tid;
        if (e0 < N_EDGES) {
            int d = dst[e0];
            int s = src[e0];
            int p = atomicAdd(&cnt[d], 1);
            if (p < CAP) bucket[(size_t)d * CAP + p] = s;
            else ovf[atomicAdd(ovfcnt, 1)] = make_int2(d, s);
        }
        if (tid < EPB - 256) {
            int e1 = ebase + 256 + tid;
            if (e1 < N_EDGES) {
                int d = dst[e1];
                int s = src[e1];
                int p = atomicAdd(&cnt[d], 1);
                if (p < CAP) bucket[(size_t)d * CAP + p] = s;
                else ovf[atomicAdd(ovfcnt, 1)] = make_int2(d, s);
            }
        }
    }

    floatx4 acc0[6], acc1[6];
#pragma unroll
    for (int t = 0; t < 6; ++t) {
        acc0[t] = (floatx4){0.f, 0.f, 0.f, 0.f};
        acc1[t] = (floatx4){0.f, 0.f, 0.f, 0.f};
    }
#pragma unroll
    for (int ks = 0; ks < 4; ++ks) {
#pragma unroll
        for (int t = 0; t < 6; ++t) {
            // swapped operands: lane owns 4 consecutive output cols
            acc0[t] = __builtin_amdgcn_mfma_f32_16x16x32_bf16(br[t * 4 + ks], a0r[ks], acc0[t], 0, 0, 0);
            acc1[t] = __builtin_amdgcn_mfma_f32_16x16x32_bf16(br[t * 4 + ks], a1r[ks], acc1[t], 0, 0, 0);
        }
    }

    // epilogue: lane's acc[t][r] = z[node][j], node=mbase+col (+16), j=(T0+t)*16+quad*4+r
    unsigned short* wlds = lds + wave * 32 * LDSROW;
#pragma unroll
    for (int t = 0; t < 6; ++t) {
        int T = T0 + t;
        float4 bq = (float4){0.f, 0.f, 0.f, 0.f};
        if (T < 8) bq = *(const float4*)(bias + T * 16 + quad * 4);
        uint2 p;
        p.x = pack2(acc0[t][0] + bq.x, acc0[t][1] + bq.y);
        p.y = pack2(acc0[t][2] + bq.z, acc0[t][3] + bq.w);
        *(uint2*)(wlds + col * LDSROW + t * 16 + quad * 4) = p;
        uint2 q2;
        q2.x = pack2(acc1[t][0] + bq.x, acc1[t][1] + bq.y);
        q2.y = pack2(acc1[t][2] + bq.z, acc1[t][3] + bq.w);
        *(uint2*)(wlds + (col + 16) * LDSROW + t * 16 + quad * 4) = q2;
    }
    __syncthreads();
    // block-wide readback: 32 rows x 48 chunks(16B) = full 768B rows, coalesced
#pragma unroll
    for (int it = 0; it < 6; ++it) {
        int id = it * 256 + tid;
        int row = id / 48;
        int ch = id - row * 48;
        int w = ch / 12;
        int cc = (ch - w * 12) * 8;  // ushort offset within wave's 96 cols
        int node = mbase + row;
        ushort8 v = *(const ushort8*)(lds + (size_t)w * 32 * LDSROW + row * LDSROW + cc);
        if (node < N_NODES)
            *(ushort8*)(z + (size_t)node * K3 + ch * 8) = v;
    }
}

// ---------------- gather1: tb = z2 + P z3  (bf16 out) ----------------
// one wave/node; lane = slot*16 + colchunk; bucket rows are 16B-aligned.
__global__ __launch_bounds__(256) void gather1_kernel(const unsigned short* __restrict__ z,
                                                      const int* __restrict__ cnt,
                                                      const int* __restrict__ bucket,
                                                      const int2* __restrict__ ovf,
                                                      unsigned short* __restrict__ tb) {
    unsigned n = (blockIdx.x * 256 + threadIdx.x) >> 6;
    if (n >= N_NODES) return;
    const int lane = threadIdx.x & 63;
    const int s = lane >> 4;
    const unsigned c = (lane & 15u) << 3;
    const unsigned short* fin = z + 256 + c;  // z3 cols
    const int deg = cnt[n];
    const int dcap = min(deg, CAP);
    const int* bp = bucket + (size_t)n * CAP;
    float acc[8] = {0.f, 0.f, 0.f, 0.f, 0.f, 0.f, 0.f, 0.f};
    for (int base = s * 4; base < dcap; base += 16) {
        int4 idx = *(const int4*)(bp + base);
        float m0 = 1.f;  // base < dcap guaranteed
        float m1 = (base + 1 < dcap) ? 1.f : 0.f;
        float m2 = (base + 2 < dcap) ? 1.f : 0.f;
        float m3 = (base + 3 < dcap) ? 1.f : 0.f;
        int s0 = min(max(idx.x, 0), N_NODES - 1);
        int s1 = min(max(idx.y, 0), N_NODES - 1);
        int s2 = min(max(idx.z, 0), N_NODES - 1);
        int s3 = min(max(idx.w, 0), N_NODES - 1);
        ushort8 v0 = *(const ushort8*)(fin + (size_t)s0 * K3);
        ushort8 v1 = *(const ushort8*)(fin + (size_t)s1 * K3);
        ushort8 v2 = *(const ushort8*)(fin + (size_t)s2 * K3);
        ushort8 v3 = *(const ushort8*)(fin + (size_t)s3 * K3);
#pragma unroll
        for (int j = 0; j < 8; ++j)
            acc[j] += (m0 * bf2f(v0[j]) + m1 * bf2f(v1[j])) +
                      (m2 * bf2f(v2[j]) + m3 * bf2f(v3[j]));
    }
    if (deg > CAP) {  // spill path (never taken for this input; correct in general)
        int oc = cnt[N_NODES];
        if (s == 0)
            for (int i = 0; i < oc; ++i) {
                int2 p = ovf[i];
                if (p.x == (int)n) {
                    ushort8 v = *(const ushort8*)(fin + (size_t)p.y * K3);
#pragma unroll
                    for (int j = 0; j < 8; ++j) acc[j] += bf2f(v[j]);
                }
            }
    }
#pragma unroll
    for (int j = 0; j < 8; ++j) {
        acc[j] += __shfl_xor(acc[j], 16);
        acc[j] += __shfl_xor(acc[j], 32);
    }
    if (s == 0) {
        float inv = 1.0f / fmaxf((float)deg, 1.0f);
        ushort8 za = *(const ushort8*)(z + (size_t)n * K3 + 128 + c);  // z2
        ushort8 o;
#pragma unroll
        for (int j = 0; j < 8; ++j) o[j] = f2bf(bf2f(za[j]) + acc[j] * inv);
        *(ushort8*)(tb + (size_t)n * D + c) = o;
    }
}

// ---------------- gather2: out = z1 + P tb  (fp32 out, final) ----------------
__global__ __launch_bounds__(256) void gather2_kernel(const unsigned short* __restrict__ z,
                                                      const unsigned short* __restrict__ tb,
                                                      const int* __restrict__ cnt,
                                                      const int* __restrict__ bucket,
                                                      const int2* __restrict__ ovf,
                                                      float* __restrict__ out) {
    unsigned n = (blockIdx.x * 256 + threadIdx.x) >> 6;
    if (n >= N_NODES) return;
    const int lane = threadIdx.x & 63;
    const int s = lane >> 4;
    const unsigned c = (lane & 15u) << 3;
    const unsigned short* fin = tb + c;
    const int deg = cnt[n];
    const int dcap = min(deg, CAP);
    const int* bp = bucket + (size_t)n * CAP;
    float acc[8] = {0.f, 0.f, 0.f, 0.f, 0.f, 0.f, 0.f, 0.f};
    for (int base = s * 4; base < dcap; base += 16) {
        int4 idx = *(const int4*)(bp + base);
        float m0 = 1.f;
        float m1 = (base + 1 < dcap) ? 1.f : 0.f;
        float m2 = (base + 2 < dcap) ? 1.f : 0.f;
        float m3 = (base + 3 < dcap) ? 1.f : 0.f;
        int s0 = min(max(idx.x, 0), N_NODES - 1);
        int s1 = min(max(idx.y, 0), N_NODES - 1);
        int s2 = min(max(idx.z, 0), N_NODES - 1);
        int s3 = min(max(idx.w, 0), N_NODES - 1);
        ushort8 v0 = *(const ushort8*)(fin + (size_t)s0 * D);
        ushort8 v1 = *(const ushort8*)(fin + (size_t)s1 * D);
        ushort8 v2 = *(const ushort8*)(fin + (size_t)s2 * D);
        ushort8 v3 = *(const ushort8*)(fin + (size_t)s3 * D);
#pragma unroll
        for (int j = 0; j < 8; ++j)
            acc[j] += (m0 * bf2f(v0[j]) + m1 * bf2f(v1[j])) +
                      (m2 * bf2f(v2[j]) + m3 * bf2f(v3[j]));
    }
    if (deg > CAP) {
        int oc = cnt[N_NODES];
        if (s == 0)
            for (int i = 0; i < oc; ++i) {
                int2 p = ovf[i];
                if (p.x == (int)n) {
                    ushort8 v = *(const ushort8*)(fin + (size_t)p.y * D);
#pragma unroll
                    for (int j = 0; j < 8; ++j) acc[j] += bf2f(v[j]);
                }
            }
    }
#pragma unroll
    for (int j = 0; j < 8; ++j) {
        acc[j] += __shfl_xor(acc[j], 16);
        acc[j] += __shfl_xor(acc[j], 32);
    }
    if (s == 0) {
        float inv = 1.0f / fmaxf((float)deg, 1.0f);
        ushort8 za = *(const ushort8*)(z + (size_t)n * K3 + c);  // z1 (+bias)
        float4 q0, q1;
        q0.x = bf2f(za[0]) + acc[0] * inv;
        q0.y = bf2f(za[1]) + acc[1] * inv;
        q0.z = bf2f(za[2]) + acc[2] * inv;
        q0.w = bf2f(za[3]) + acc[3] * inv;
        q1.x = bf2f(za[4]) + acc[4] * inv;
        q1.y = bf2f(za[5]) + acc[5] * inv;
        q1.z = bf2f(za[6]) + acc[6] * inv;
        q1.w = bf2f(za[7]) + acc[7] * inv;
        *(float4*)(out + (size_t)n * D + c) = q0;
        *(float4*)(out + (size_t)n * D + c + 4) = q1;
    }
}

extern "C" void kernel_launch(void* const* d_in, const int* in_sizes, int n_in,
                              void* d_out, int out_size, void* d_ws, size_t ws_size,
                              hipStream_t stream) {
    const float* x = (const float*)d_in[0];
    const int* ei = (const int*)d_in[1];
    const float* W = (const float*)d_in[2];
    const float* b = (const float*)d_in[3];
    float* out = (float*)d_out;
    const int* src = ei;            // edge_index[0,:]
    const int* dst = ei + N_EDGES;  // edge_index[1,:]

    // workspace layout:
    //   z [N,384] bf16 | tb [N,128] bf16 | Wr 6144x16B
    //   cnt [N] + ovfcnt [4] | bucket [N*64] | ovf [E int2]
    unsigned short* z = (unsigned short*)d_ws;
    unsigned short* tb = z + (size_t)N_NODES * K3;
    unsigned short* Wr = tb + (size_t)N_NODES * D;
    int* cnt = (int*)(Wr + 6144 * 8);
    int* bucket = cnt + N_NODES + 4;          // 16B-aligned (N+4 ints from aligned base)
    int2* ovf = (int2*)(bucket + (size_t)N_NODES * CAP);

    prep_kernel<<<200, 256, 0, stream>>>(W, Wr, cnt);
    gemmfill_kernel<<<NB_G, 256, 0, stream>>>(x, Wr, b, src, dst, cnt, bucket, ovf, z);

    const int ggrid = (N_NODES * 64 + 255) / 256;  // one wave per node
    gather1_kernel<<<ggrid, 256, 0, stream>>>(z, cnt, bucket, ovf, tb);
    gather2_kernel<<<ggrid, 256, 0, stream>>>(z, tb, cnt, bucket, ovf, out);
}

// Round 14
// 174.343 us; speedup vs baseline: 1.1657x; 1.0038x over previous
//
#include <hip/hip_runtime.h>

#define N_NODES 50000
#define N_EDGES 600000
#define D 128
#define K3 (3 * D)
#define CAP 64      // bucket capacity per node (mean deg 12; spill path for overflow)
#define NB_G 1563   // ceil(50000/32): one 32-row gemm tile per block (max TLP)
#define EPB 384     // edges per gemm block: 1563*384 = 600,192 >= N_EDGES
#define LDSROW 104  // 96 cols + 8 pad (ushorts); row stride 208B

typedef __attribute__((ext_vector_type(8))) short short8;
typedef __attribute__((ext_vector_type(4))) float floatx4;
typedef __attribute__((ext_vector_type(8))) unsigned short ushort8;

static __device__ __forceinline__ unsigned short f2bf(float f) {
    unsigned u = __float_as_uint(f);
    u += 0x7fff + ((u >> 16) & 1);  // RNE
    return (unsigned short)(u >> 16);
}
static __device__ __forceinline__ float bf2f(unsigned short s) {
    return __uint_as_float(((unsigned)s) << 16);
}
static __device__ __forceinline__ unsigned pack2(float a, float b) {
    return (unsigned)f2bf(a) | ((unsigned)f2bf(b) << 16);
}
static __device__ __forceinline__ short8 cvt8(float4 v0, float4 v1) {
    ushort8 o;
    o[0] = f2bf(v0.x); o[1] = f2bf(v0.y); o[2] = f2bf(v0.z); o[3] = f2bf(v0.w);
    o[4] = f2bf(v1.x); o[5] = f2bf(v1.y); o[6] = f2bf(v1.z); o[7] = f2bf(v1.w);
    return *(short8*)&o;
}

// ---------------- prep: zero cnt+ovfcnt | W->frag-ordered Wr (tiny) -------------
__global__ __launch_bounds__(256) void prep_kernel(const float* __restrict__ W,
                                                   unsigned short* __restrict__ Wr,
                                                   int* __restrict__ cnt) {
    const int stride = gridDim.x * 256;
    const int t0 = blockIdx.x * 256 + threadIdx.x;
    for (int i = t0; i < N_NODES + 4; i += stride) cnt[i] = 0;  // cnt[N] + ovfcnt
    // Wr chunk id = (T*4+ks)*64+lane; value[j] = W[(T&7)*16+c][(T>>3)*128+ks*32+q*8+j]
    for (unsigned id = t0; id < 24u * 4u * 64u; id += stride) {
        unsigned T = id >> 8;
        unsigned ks = (id >> 6) & 3u;
        unsigned lane = id & 63u;
        unsigned c = lane & 15u;
        unsigned q = lane >> 4;
        unsigned row = (T & 7u) * 16u + c;
        unsigned k = (T >> 3) * 128u + ks * 32u + q * 8u;
        const float4 v0 = *(const float4*)(W + (size_t)row * K3 + k);
        const float4 v1 = *(const float4*)(W + (size_t)row * K3 + k + 4);
        short8 o = cvt8(v0, v1);
        *(short8*)(Wr + (size_t)id * 8) = o;
    }
}

// ------- GEMM + pipelined bucket-CSR fill (single code path, R11 lesson) --------
// Fill split into 3 phases woven around the GEMM so its dependent chain
// (dst load -> atomicAdd -> p -> store) never sits exposed on the critical path:
//   A: issue dst/src loads FIRST (hide under A-frag loads+convert)
//   B: issue atomicAdds after frag loads (d ready; round-trip hides under MFMA)
//   C: consume p for bucket stores AFTER the MFMA loop (p ready by then)
// VGPR canary: must stay >~120 (R11: regalloc dropping br[24] costs 2x).
__global__ __launch_bounds__(256) void gemmfill_kernel(const float* __restrict__ x,
                                                       const unsigned short* __restrict__ Wr,
                                                       const float* __restrict__ bias,
                                                       const int* __restrict__ src,
                                                       const int* __restrict__ dst,
                                                       int* __restrict__ cnt,
                                                       int* __restrict__ bucket,
                                                       int2* __restrict__ ovf,
                                                       unsigned short* __restrict__ z) {
    __shared__ unsigned short lds[4 * 32 * LDSROW];
    const int tid = threadIdx.x;
    const int wave = tid >> 6;
    const int lane = tid & 63;
    const int col = lane & 15;
    const int quad = lane >> 4;
    const int mbase = blockIdx.x * 32;
    const int T0 = wave * 6;  // colblocks [T0, T0+6) => global cols [wave*96, +96)

    // ---- fill phase A: issue this block's edge loads first ----
    int d0 = 0, s0 = 0, d1 = 0, s1 = 0;
    bool v0, v1;
    {
        const int ebase = blockIdx.x * EPB;
        int e0 = ebase + tid;
        v0 = (e0 < N_EDGES);
        if (v0) { d0 = dst[e0]; s0 = src[e0]; }
        int e1 = ebase + 256 + tid;
        v1 = (tid < EPB - 256) && (e1 < N_EDGES);
        if (v1) { d1 = dst[e1]; s1 = src[e1]; }
    }

    int r0 = mbase + col;
    int r1 = mbase + 16 + col;
    if (r0 >= N_NODES) r0 = N_NODES - 1;  // clamp loads; stores guarded
    if (r1 >= N_NODES) r1 = N_NODES - 1;
    const float* ap0 = x + (size_t)r0 * D + quad * 8;
    const float* ap1 = x + (size_t)r1 * D + quad * 8;

    // A fragments: fp32 load + in-register bf16 convert (no staging)
    short8 a0r[4], a1r[4];
#pragma unroll
    for (int ks = 0; ks < 4; ++ks) {
        a0r[ks] = cvt8(*(const float4*)(ap0 + ks * 32), *(const float4*)(ap0 + ks * 32 + 4));
        a1r[ks] = cvt8(*(const float4*)(ap1 + ks * 32), *(const float4*)(ap1 + ks * 32 + 4));
    }
    // B fragments for this wave's 96 columns (L2-resident Wr)
    short8 br[24];
#pragma unroll
    for (int t = 0; t < 6; ++t)
#pragma unroll
        for (int ks = 0; ks < 4; ++ks)
            br[t * 4 + ks] = *(const short8*)(Wr + (size_t)(((T0 + t) * 4 + ks) * 64 + lane) * 8);

    // ---- fill phase B: issue cursor atomics (d arrived during frag loads) ----
    int p0 = 0, p1 = 0;
    if (v0) p0 = atomicAdd(&cnt[d0], 1);
    if (v1) p1 = atomicAdd(&cnt[d1], 1);

    floatx4 acc0[6], acc1[6];
#pragma unroll
    for (int t = 0; t < 6; ++t) {
        acc0[t] = (floatx4){0.f, 0.f, 0.f, 0.f};
        acc1[t] = (floatx4){0.f, 0.f, 0.f, 0.f};
    }
#pragma unroll
    for (int ks = 0; ks < 4; ++ks) {
#pragma unroll
        for (int t = 0; t < 6; ++t) {
            // swapped operands: lane owns 4 consecutive output cols
            acc0[t] = __builtin_amdgcn_mfma_f32_16x16x32_bf16(br[t * 4 + ks], a0r[ks], acc0[t], 0, 0, 0);
            acc1[t] = __builtin_amdgcn_mfma_f32_16x16x32_bf16(br[t * 4 + ks], a1r[ks], acc1[t], 0, 0, 0);
        }
    }

    // ---- fill phase C: bucket stores (atomic results ready; hidden under MFMA) --
    {
        int* ovfcnt = cnt + N_NODES;
        if (v0) {
            if (p0 < CAP) bucket[(size_t)d0 * CAP + p0] = s0;
            else ovf[atomicAdd(ovfcnt, 1)] = make_int2(d0, s0);
        }
        if (v1) {
            if (p1 < CAP) bucket[(size_t)d1 * CAP + p1] = s1;
            else ovf[atomicAdd(ovfcnt, 1)] = make_int2(d1, s1);
        }
    }

    // epilogue: lane's acc[t][r] = z[node][j], node=mbase+col (+16), j=(T0+t)*16+quad*4+r
    unsigned short* wlds = lds + wave * 32 * LDSROW;
#pragma unroll
    for (int t = 0; t < 6; ++t) {
        int T = T0 + t;
        float4 bq = (float4){0.f, 0.f, 0.f, 0.f};
        if (T < 8) bq = *(const float4*)(bias + T * 16 + quad * 4);
        uint2 p;
        p.x = pack2(acc0[t][0] + bq.x, acc0[t][1] + bq.y);
        p.y = pack2(acc0[t][2] + bq.z, acc0[t][3] + bq.w);
        *(uint2*)(wlds + col * LDSROW + t * 16 + quad * 4) = p;
        uint2 q2;
        q2.x = pack2(acc1[t][0] + bq.x, acc1[t][1] + bq.y);
        q2.y = pack2(acc1[t][2] + bq.z, acc1[t][3] + bq.w);
        *(uint2*)(wlds + (col + 16) * LDSROW + t * 16 + quad * 4) = q2;
    }
    __syncthreads();
    // block-wide readback: 32 rows x 48 chunks(16B) = full 768B rows, coalesced
#pragma unroll
    for (int it = 0; it < 6; ++it) {
        int id = it * 256 + tid;
        int row = id / 48;
        int ch = id - row * 48;
        int w = ch / 12;
        int cc = (ch - w * 12) * 8;  // ushort offset within wave's 96 cols
        int node = mbase + row;
        ushort8 v = *(const ushort8*)(lds + (size_t)w * 32 * LDSROW + row * LDSROW + cc);
        if (node < N_NODES)
            *(ushort8*)(z + (size_t)node * K3 + ch * 8) = v;
    }
}

// ---------------- gather1: tb = z2 + P z3  (bf16 out) ----------------
// one wave/node; lane = slot*16 + colchunk; bucket rows are 16B-aligned.
__global__ __launch_bounds__(256) void gather1_kernel(const unsigned short* __restrict__ z,
                                                      const int* __restrict__ cnt,
                                                      const int* __restrict__ bucket,
                                                      const int2* __restrict__ ovf,
                                                      unsigned short* __restrict__ tb) {
    unsigned n = (blockIdx.x * 256 + threadIdx.x) >> 6;
    if (n >= N_NODES) return;
    const int lane = threadIdx.x & 63;
    const int s = lane >> 4;
    const unsigned c = (lane & 15u) << 3;
    const unsigned short* fin = z + 256 + c;  // z3 cols
    const int deg = cnt[n];
    const int dcap = min(deg, CAP);
    const int* bp = bucket + (size_t)n * CAP;
    float acc[8] = {0.f, 0.f, 0.f, 0.f, 0.f, 0.f, 0.f, 0.f};
    for (int base = s * 4; base < dcap; base += 16) {
        int4 idx = *(const int4*)(bp + base);
        float m0 = 1.f;  // base < dcap guaranteed
        float m1 = (base + 1 < dcap) ? 1.f : 0.f;
        float m2 = (base + 2 < dcap) ? 1.f : 0.f;
        float m3 = (base + 3 < dcap) ? 1.f : 0.f;
        int s0 = min(max(idx.x, 0), N_NODES - 1);
        int s1 = min(max(idx.y, 0), N_NODES - 1);
        int s2 = min(max(idx.z, 0), N_NODES - 1);
        int s3 = min(max(idx.w, 0), N_NODES - 1);
        ushort8 v0 = *(const ushort8*)(fin + (size_t)s0 * K3);
        ushort8 v1 = *(const ushort8*)(fin + (size_t)s1 * K3);
        ushort8 v2 = *(const ushort8*)(fin + (size_t)s2 * K3);
        ushort8 v3 = *(const ushort8*)(fin + (size_t)s3 * K3);
#pragma unroll
        for (int j = 0; j < 8; ++j)
            acc[j] += (m0 * bf2f(v0[j]) + m1 * bf2f(v1[j])) +
                      (m2 * bf2f(v2[j]) + m3 * bf2f(v3[j]));
    }
    if (deg > CAP) {  // spill path (never taken for this input; correct in general)
        int oc = cnt[N_NODES];
        if (s == 0)
            for (int i = 0; i < oc; ++i) {
                int2 p = ovf[i];
                if (p.x == (int)n) {
                    ushort8 v = *(const ushort8*)(fin + (size_t)p.y * K3);
#pragma unroll
                    for (int j = 0; j < 8; ++j) acc[j] += bf2f(v[j]);
                }
            }
    }
#pragma unroll
    for (int j = 0; j < 8; ++j) {
        acc[j] += __shfl_xor(acc[j], 16);
        acc[j] += __shfl_xor(acc[j], 32);
    }
    if (s == 0) {
        float inv = 1.0f / fmaxf((float)deg, 1.0f);
        ushort8 za = *(const ushort8*)(z + (size_t)n * K3 + 128 + c);  // z2
        ushort8 o;
#pragma unroll
        for (int j = 0; j < 8; ++j) o[j] = f2bf(bf2f(za[j]) + acc[j] * inv);
        *(ushort8*)(tb + (size_t)n * D + c) = o;
    }
}

// ---------------- gather2: out = z1 + P tb  (fp32 out, final) ----------------
__global__ __launch_bounds__(256) void gather2_kernel(const unsigned short* __restrict__ z,
                                                      const unsigned short* __restrict__ tb,
                                                      const int* __restrict__ cnt,
                                                      const int* __restrict__ bucket,
                                                      const int2* __restrict__ ovf,
                                                      float* __restrict__ out) {
    unsigned n = (blockIdx.x * 256 + threadIdx.x) >> 6;
    if (n >= N_NODES) return;
    const int lane = threadIdx.x & 63;
    const int s = lane >> 4;
    const unsigned c = (lane & 15u) << 3;
    const unsigned short* fin = tb + c;
    const int deg = cnt[n];
    const int dcap = min(deg, CAP);
    const int* bp = bucket + (size_t)n * CAP;
    float acc[8] = {0.f, 0.f, 0.f, 0.f, 0.f, 0.f, 0.f, 0.f};
    for (int base = s * 4; base < dcap; base += 16) {
        int4 idx = *(const int4*)(bp + base);
        float m0 = 1.f;
        float m1 = (base + 1 < dcap) ? 1.f : 0.f;
        float m2 = (base + 2 < dcap) ? 1.f : 0.f;
        float m3 = (base + 3 < dcap) ? 1.f : 0.f;
        int s0 = min(max(idx.x, 0), N_NODES - 1);
        int s1 = min(max(idx.y, 0), N_NODES - 1);
        int s2 = min(max(idx.z, 0), N_NODES - 1);
        int s3 = min(max(idx.w, 0), N_NODES - 1);
        ushort8 v0 = *(const ushort8*)(fin + (size_t)s0 * D);
        ushort8 v1 = *(const ushort8*)(fin + (size_t)s1 * D);
        ushort8 v2 = *(const ushort8*)(fin + (size_t)s2 * D);
        ushort8 v3 = *(const ushort8*)(fin + (size_t)s3 * D);
#pragma unroll
        for (int j = 0; j < 8; ++j)
            acc[j] += (m0 * bf2f(v0[j]) + m1 * bf2f(v1[j])) +
                      (m2 * bf2f(v2[j]) + m3 * bf2f(v3[j]));
    }
    if (deg > CAP) {
        int oc = cnt[N_NODES];
        if (s == 0)
            for (int i = 0; i < oc; ++i) {
                int2 p = ovf[i];
                if (p.x == (int)n) {
                    ushort8 v = *(const ushort8*)(fin + (size_t)p.y * D);
#pragma unroll
                    for (int j = 0; j < 8; ++j) acc[j] += bf2f(v[j]);
                }
            }
    }
#pragma unroll
    for (int j = 0; j < 8; ++j) {
        acc[j] += __shfl_xor(acc[j], 16);
        acc[j] += __shfl_xor(acc[j], 32);
    }
    if (s == 0) {
        float inv = 1.0f / fmaxf((float)deg, 1.0f);
        ushort8 za = *(const ushort8*)(z + (size_t)n * K3 + c);  // z1 (+bias)
        float4 q0, q1;
        q0.x = bf2f(za[0]) + acc[0] * inv;
        q0.y = bf2f(za[1]) + acc[1] * inv;
        q0.z = bf2f(za[2]) + acc[2] * inv;
        q0.w = bf2f(za[3]) + acc[3] * inv;
        q1.x = bf2f(za[4]) + acc[4] * inv;
        q1.y = bf2f(za[5]) + acc[5] * inv;
        q1.z = bf2f(za[6]) + acc[6] * inv;
        q1.w = bf2f(za[7]) + acc[7] * inv;
        *(float4*)(out + (size_t)n * D + c) = q0;
        *(float4*)(out + (size_t)n * D + c + 4) = q1;
    }
}

extern "C" void kernel_launch(void* const* d_in, const int* in_sizes, int n_in,
                              void* d_out, int out_size, void* d_ws, size_t ws_size,
                              hipStream_t stream) {
    const float* x = (const float*)d_in[0];
    const int* ei = (const int*)d_in[1];
    const float* W = (const float*)d_in[2];
    const float* b = (const float*)d_in[3];
    float* out = (float*)d_out;
    const int* src = ei;            // edge_index[0,:]
    const int* dst = ei + N_EDGES;  // edge_index[1,:]

    // workspace layout:
    //   z [N,384] bf16 | tb [N,128] bf16 | Wr 6144x16B
    //   cnt [N] + ovfcnt [4] | bucket [N*64] | ovf [E int2]
    unsigned short* z = (unsigned short*)d_ws;
    unsigned short* tb = z + (size_t)N_NODES * K3;
    unsigned short* Wr = tb + (size_t)N_NODES * D;
    int* cnt = (int*)(Wr + 6144 * 8);
    int* bucket = cnt + N_NODES + 4;          // 16B-aligned (N+4 ints from aligned base)
    int2* ovf = (int2*)(bucket + (size_t)N_NODES * CAP);

    prep_kernel<<<200, 256, 0, stream>>>(W, Wr, cnt);
    gemmfill_kernel<<<NB_G, 256, 0, stream>>>(x, Wr, b, src, dst, cnt, bucket, ovf, z);

    const int ggrid = (N_NODES * 64 + 255) / 256;  // one wave per node
    gather1_kernel<<<ggrid, 256, 0, stream>>>(z, cnt, bucket, ovf, tb);
    gather2_kernel<<<ggrid, 256, 0, stream>>>(z, tb, cnt, bucket, ovf, out);
}